// Round 5
// baseline (1588.578 us; speedup 1.0000x reference)
//
#include <hip/hip_runtime.h>
#include <hip/hip_bf16.h>

// Problem sizes (fixed by the reference)
#define B_ 8192
#define D_ 512
#define H_ 1024
#define S_ 4096
#define Y_ 256

// Output element offsets (fp32 elements) in return order:
// mu, Z, soft_prob, soft_prob_y, hard_prob, batch_y   (d_out is FLOAT32)
constexpr size_t O_MU    = 0;
constexpr size_t O_Z     = (size_t)B_ * D_;
constexpr size_t O_SOFT  = O_Z + (size_t)B_ * D_;
constexpr size_t O_SOFTY = O_SOFT + (size_t)B_ * S_;
constexpr size_t O_HARD  = O_SOFTY + (size_t)B_ * Y_;
constexpr size_t O_BY    = O_HARD + (size_t)B_ * S_;

// ---------------------------------------------------------------------------
// helpers
// ---------------------------------------------------------------------------
__device__ __forceinline__ float blockMax(float v, float* sh) {
#pragma unroll
  for (int o = 32; o; o >>= 1) v = fmaxf(v, __shfl_xor(v, o));
  if ((threadIdx.x & 63) == 0) sh[threadIdx.x >> 6] = v;
  __syncthreads();
  float r = fmaxf(fmaxf(sh[0], sh[1]), fmaxf(sh[2], sh[3]));
  __syncthreads();
  return r;
}

__device__ __forceinline__ float blockSum(float v, float* sh) {
#pragma unroll
  for (int o = 32; o; o >>= 1) v += __shfl_xor(v, o);
  if ((threadIdx.x & 63) == 0) sh[threadIdx.x >> 6] = v;
  __syncthreads();
  float r = (sh[0] + sh[1]) + (sh[2] + sh[3]);
  __syncthreads();
  return r;
}

// max value, ties -> smallest index (replicates jnp.argmax first-occurrence)
__device__ __forceinline__ void blockArgmax(float& v, int& i, float* shf, int* shi) {
#pragma unroll
  for (int o = 32; o; o >>= 1) {
    float v2 = __shfl_xor(v, o);
    int   i2 = __shfl_xor(i, o);
    if (v2 > v || (v2 == v && i2 < i)) { v = v2; i = i2; }
  }
  if ((threadIdx.x & 63) == 0) { shf[threadIdx.x >> 6] = v; shi[threadIdx.x >> 6] = i; }
  __syncthreads();
  float bv = shf[0]; int bi = shi[0];
#pragma unroll
  for (int k = 1; k < 4; ++k) {
    float v2 = shf[k]; int i2 = shi[k];
    if (v2 > bv || (v2 == bv && i2 < bi)) { bv = v2; bi = i2; }
  }
  v = bv; i = bi;
  __syncthreads();
}

// per-row squared norms (4 waves/block, one row per wave)
__global__ void rownorm_kernel(const float* __restrict__ A, int rows, int K,
                               float* __restrict__ out) {
  int w = threadIdx.x >> 6, lane = threadIdx.x & 63;
  int row = blockIdx.x * 4 + w;
  if (row >= rows) return;
  const float* a = A + (size_t)row * K;
  float s = 0.f;
  for (int k = lane; k < K; k += 64) { float x = a[k]; s += x * x; }
#pragma unroll
  for (int o = 32; o; o >>= 1) s += __shfl_xor(s, o);
  if (lane == 0) out[row] = s;
}

// ---------------------------------------------------------------------------
// fp32 tiled GEMM
//   NT=false: C[m][n] = sum_k A[m][k] * W[k][n]      (W natural [K][N])
//   NT=true : C[m][n] = sum_k A[m][k] * Bm[n][k]     (Bm natural [N][K])
// 128x128 tile, BK=16, block 16x16, each thread an 8x8 micro-tile.
// EPI 0: relu(c+bias)          -> Cf
// EPI 1: c+bias                -> Cf
// EPI 2: 2c - rown[m]-coln[n]  -> Cf   (-||a-b||^2 logits)
// ---------------------------------------------------------------------------
template <int EPI, bool NT>
__launch_bounds__(256)
__global__ void gemm_f32(const float* __restrict__ A, const float* __restrict__ Bm,
                         int M, int N, int K,
                         const float* __restrict__ bias,
                         float* __restrict__ Cf,
                         const float* __restrict__ rown, const float* __restrict__ coln) {
  __shared__ float As[16][129];
  __shared__ float Bs[16][129];
  const int tid = threadIdx.y * 16 + threadIdx.x;
  const int tx = threadIdx.x, ty = threadIdx.y;
  const int m0 = blockIdx.y * 128, n0 = blockIdx.x * 128;

  float acc[8][8] = {};

  for (int k0 = 0; k0 < K; k0 += 16) {
    // A tile: 128 rows x 16 k. thread: row tid/2, k = (tid&1)*8 + i
    {
      int m = tid >> 1, kb = (tid & 1) * 8;
      const float* src = A + (size_t)(m0 + m) * K + k0 + kb;
#pragma unroll
      for (int i = 0; i < 8; ++i) As[kb + i][m] = src[i];
    }
    if (NT) {
      int n = tid >> 1, kb = (tid & 1) * 8;
      const float* src = Bm + (size_t)(n0 + n) * K + k0 + kb;
#pragma unroll
      for (int i = 0; i < 8; ++i) Bs[kb + i][n] = src[i];
    } else {
      int k = tid >> 4, nb = (tid & 15) * 8;
      const float* src = Bm + (size_t)(k0 + k) * N + n0 + nb;
#pragma unroll
      for (int i = 0; i < 8; ++i) Bs[k][nb + i] = src[i];
    }
    __syncthreads();

#pragma unroll
    for (int kk = 0; kk < 16; ++kk) {
      float a[8], b[8];
#pragma unroll
      for (int i = 0; i < 8; ++i) a[i] = As[kk][ty * 8 + i];
#pragma unroll
      for (int j = 0; j < 8; ++j) b[j] = Bs[kk][tx * 8 + j];
#pragma unroll
      for (int i = 0; i < 8; ++i)
#pragma unroll
        for (int j = 0; j < 8; ++j) acc[i][j] = fmaf(a[i], b[j], acc[i][j]);
    }
    __syncthreads();
  }

#pragma unroll
  for (int i = 0; i < 8; ++i) {
    int m = m0 + ty * 8 + i;
#pragma unroll
    for (int j = 0; j < 8; ++j) {
      int n = n0 + tx * 8 + j;
      float c = acc[i][j];
      size_t idx = (size_t)m * N + n;
      if (EPI == 0) {
        Cf[idx] = fmaxf(c + bias[n], 0.0f);
      } else if (EPI == 1) {
        Cf[idx] = c + bias[n];
      } else {
        Cf[idx] = 2.0f * c - rown[m] - coln[n];
      }
    }
  }
}

// ---------------------------------------------------------------------------
// Z = mu + softplus(ps)*eps ; writes mu,Z (fp32 out), Z fp32 ws, ||Z||^2
// ---------------------------------------------------------------------------
__global__ __launch_bounds__(256) void kz_kernel(const float* __restrict__ mu,
                                                 const float* __restrict__ ps,
                                                 const float* __restrict__ eps,
                                                 float* __restrict__ out,
                                                 float* __restrict__ Zf,
                                                 float* __restrict__ z2) {
  __shared__ float sh[4];
  int row = blockIdx.x, t = threadIdx.x;
  float s = 0.f;
  for (int j = t; j < D_; j += 256) {
    size_t idx = (size_t)row * D_ + j;
    float m = mu[idx], p = ps[idx], e = eps[idx];
    float sp = fmaxf(p, 0.f) + log1pf(expf(-fabsf(p)));  // stable softplus
    float z = m + sp * e;
    out[O_MU + idx] = m;
    out[O_Z + idx] = z;
    Zf[idx] = z;
    s += z * z;
  }
#pragma unroll
  for (int o = 32; o; o >>= 1) s += __shfl_xor(s, o);
  if ((t & 63) == 0) sh[t >> 6] = s;
  __syncthreads();
  if (t == 0) z2[row] = (sh[0] + sh[1]) + (sh[2] + sh[3]);
}

// ---------------------------------------------------------------------------
// fine routing: per-row double softmax + gumbel + argmax over S=4096
// ---------------------------------------------------------------------------
__global__ __launch_bounds__(256) void ks_kernel(const float* __restrict__ logits,
                                                 const float* __restrict__ us,
                                                 float* __restrict__ out,
                                                 int* __restrict__ fidx) {
  __shared__ float shf[4];
  __shared__ int shi[4];
  int row = blockIdx.x, t = threadIdx.x;
  const float* l = logits + (size_t)row * S_;
  const float* u = us + (size_t)row * S_;

  float v[16];
  float m1 = -3.4e38f;
#pragma unroll
  for (int k = 0; k < 16; ++k) { v[k] = l[t + k * 256]; m1 = fmaxf(m1, v[k]); }
  m1 = blockMax(m1, shf);
  float s1 = 0.f;
#pragma unroll
  for (int k = 0; k < 16; ++k) { v[k] = expf(v[k] - m1); s1 += v[k]; }
  s1 = blockSum(s1, shf);
  float m2 = -3.4e38f;
#pragma unroll
  for (int k = 0; k < 16; ++k) {
    float p = v[k] / s1 + 1e-9f;                       // softmax + 1e-9
    float uu = u[t + k * 256];
    float g = -logf(-logf(uu + 1e-20f) + 1e-20f);      // gumbel noise
    v[k] = (logf(p) + g) * 2.0f;                       // (log p + g)/0.5
    m2 = fmaxf(m2, v[k]);
  }
  m2 = blockMax(m2, shf);
  float s2 = 0.f;
#pragma unroll
  for (int k = 0; k < 16; ++k) { v[k] = expf(v[k] - m2); s2 += v[k]; }
  s2 = blockSum(s2, shf);
  float bv = -3.4e38f; int bi = 0x7fffffff;
#pragma unroll
  for (int k = 0; k < 16; ++k) {
    float p = v[k] / s2;
    out[O_SOFT + (size_t)row * S_ + t + k * 256] = p;
    if (p > bv) { bv = p; bi = t + k * 256; }          // ascending j: > keeps first
  }
  blockArgmax(bv, bi, shf, shi);
#pragma unroll
  for (int k = 0; k < 16; ++k) {
    int j = t + k * 256;
    out[O_HARD + (size_t)row * S_ + j] = (j == bi) ? 1.0f : 0.0f;
  }
  if (t == 0) fidx[row] = bi;
}

// ---------------------------------------------------------------------------
// coarse routing: logits = 0.5*(lzy[row] + lsy[fine_idx]); gumbel; argmax
// ---------------------------------------------------------------------------
__global__ __launch_bounds__(256) void ky_kernel(const float* __restrict__ lzy,
                                                 const float* __restrict__ lsy,
                                                 const int* __restrict__ fidx,
                                                 const float* __restrict__ uy,
                                                 float* __restrict__ out) {
  __shared__ float shf[4];
  __shared__ int shi[4];
  int row = blockIdx.x, t = threadIdx.x;  // Y_ == 256 == blockDim
  int fi = fidx[row];
  float lc = 0.5f * (lzy[(size_t)row * Y_ + t] + lsy[(size_t)fi * Y_ + t]);
  float m1 = blockMax(lc, shf);
  float e = expf(lc - m1);
  float s1 = blockSum(e, shf);
  float p = e / s1 + 1e-9f;
  float g = -logf(-logf(uy[(size_t)row * Y_ + t] + 1e-20f) + 1e-20f);
  float a = (logf(p) + g) * 2.0f;
  float m2 = blockMax(a, shf);
  float y = expf(a - m2);
  float s2 = blockSum(y, shf);
  float sp = y / s2;
  out[O_SOFTY + (size_t)row * Y_ + t] = sp;
  float bv = sp; int bi = t;
  blockArgmax(bv, bi, shf, shi);
  if (t == 0) out[O_BY + row] = (float)bi;
}

// ---------------------------------------------------------------------------
// launch
// ---------------------------------------------------------------------------
extern "C" void kernel_launch(void* const* d_in, const int* in_sizes, int n_in,
                              void* d_out, int out_size, void* d_ws, size_t ws_size,
                              hipStream_t stream) {
  const float* X    = (const float*)d_in[0];
  const float* W1   = (const float*)d_in[1];
  const float* b1   = (const float*)d_in[2];
  const float* W2   = (const float*)d_in[3];
  const float* b2   = (const float*)d_in[4];
  const float* Ws1  = (const float*)d_in[5];
  const float* bs1  = (const float*)d_in[6];
  const float* Ws2  = (const float*)d_in[7];
  const float* bs2  = (const float*)d_in[8];
  const float* mu_y = (const float*)d_in[9];
  const float* mu_s = (const float*)d_in[10];
  const float* eps  = (const float*)d_in[11];
  const float* u_s  = (const float*)d_in[12];
  const float* u_y  = (const float*)d_in[13];
  float* out = (float*)d_out;   // OUTPUT dtype is FLOAT32 (ref returns fp32)

  // Workspace (~156 MB peak): LOGITS@[0,128MB) overlaps region A, which is
  // fully dead before gemm<2> writes LOGITS (kz consumes MUF/PSF first).
  char* ws = (char*)d_ws;
  float* LOGITS = (float*)ws;  // [0, 128MB)
  size_t offA = 0;
  auto allocA = [&](size_t bytes) -> void* {
    void* p = ws + offA;
    offA += (bytes + 4095) & ~(size_t)4095;
    return p;
  };
  float* H1  = (float*)allocA((size_t)B_ * H_ * 4);   // 32MB
  float* S1  = (float*)allocA((size_t)B_ * H_ * 4);   // 32MB
  float* MUF = (float*)allocA((size_t)B_ * D_ * 4);   // 16MB
  float* PSF = (float*)allocA((size_t)B_ * D_ * 4);   // 16MB (total 96MB < 128MB)
  size_t offB = ((size_t)B_ * S_ * 4 + 4095) & ~(size_t)4095;  // 128MB
  auto allocB = [&](size_t bytes) -> void* {
    void* p = ws + offB;
    offB += (bytes + 4095) & ~(size_t)4095;
    return p;
  };
  float* ZF  = (float*)allocB((size_t)B_ * D_ * 4);   // 16MB
  float* Z2  = (float*)allocB((size_t)B_ * 4);
  float* CS2 = (float*)allocB((size_t)S_ * 4);
  float* CY2 = (float*)allocB((size_t)Y_ * 4);
  int*   FIDX = (int*)allocB((size_t)B_ * 4);
  float* LZY = (float*)allocB((size_t)B_ * Y_ * 4);   // 8MB
  float* LSY = (float*)allocB((size_t)S_ * Y_ * 4);   // 4MB
  (void)ws_size; (void)in_sizes; (void)n_in; (void)out_size;

  // 1) codebook norms
  rownorm_kernel<<<S_ / 4, 256, 0, stream>>>(mu_s, S_, D_, CS2);
  rownorm_kernel<<<Y_ / 4, 256, 0, stream>>>(mu_y, Y_, D_, CY2);

  // 2) encoder GEMMs (fp32, W in natural [K][N] layout)
  gemm_f32<0, false><<<dim3(H_ / 128, B_ / 128), dim3(16, 16), 0, stream>>>(
      X, W1, B_, H_, D_, b1, H1, nullptr, nullptr);
  gemm_f32<0, false><<<dim3(H_ / 128, B_ / 128), dim3(16, 16), 0, stream>>>(
      X, Ws1, B_, H_, D_, bs1, S1, nullptr, nullptr);
  gemm_f32<1, false><<<dim3(D_ / 128, B_ / 128), dim3(16, 16), 0, stream>>>(
      H1, W2, B_, D_, H_, b2, MUF, nullptr, nullptr);
  gemm_f32<1, false><<<dim3(D_ / 128, B_ / 128), dim3(16, 16), 0, stream>>>(
      S1, Ws2, B_, D_, H_, bs2, PSF, nullptr, nullptr);

  // 3) reparameterize
  kz_kernel<<<B_, 256, 0, stream>>>(MUF, PSF, eps, out, ZF, Z2);

  // 4) distance logits (NT: codebooks already [N][K])
  gemm_f32<2, true><<<dim3(S_ / 128, B_ / 128), dim3(16, 16), 0, stream>>>(
      ZF, mu_s, B_, S_, D_, nullptr, LOGITS, Z2, CS2);
  gemm_f32<2, true><<<dim3(Y_ / 128, B_ / 128), dim3(16, 16), 0, stream>>>(
      ZF, mu_y, B_, Y_, D_, nullptr, LZY, Z2, CY2);
  gemm_f32<2, true><<<dim3(Y_ / 128, S_ / 128), dim3(16, 16), 0, stream>>>(
      mu_s, mu_y, S_, Y_, D_, nullptr, LSY, CS2, CY2);

  // 5) routing
  ks_kernel<<<B_, 256, 0, stream>>>(LOGITS, u_s, out, FIDX);
  ky_kernel<<<B_, 256, 0, stream>>>(LZY, LSY, FIDX, u_y, out);
}

// Round 6
// 455.033 us; speedup vs baseline: 3.4911x; 3.4911x over previous
//
#include <hip/hip_runtime.h>
#include <hip/hip_bf16.h>

// Problem sizes (fixed by the reference)
#define B_ 8192
#define D_ 512
#define H_ 1024
#define S_ 4096
#define Y_ 256

// Output element offsets (fp32 elements) in return order:
// mu, Z, soft_prob, soft_prob_y, hard_prob, batch_y   (d_out is FLOAT32)
constexpr size_t O_MU    = 0;
constexpr size_t O_Z     = (size_t)B_ * D_;
constexpr size_t O_SOFT  = O_Z + (size_t)B_ * D_;
constexpr size_t O_SOFTY = O_SOFT + (size_t)B_ * S_;
constexpr size_t O_HARD  = O_SOFTY + (size_t)B_ * Y_;
constexpr size_t O_BY    = O_HARD + (size_t)B_ * S_;

typedef _Float16 half8 __attribute__((ext_vector_type(8)));
typedef float f32x4 __attribute__((ext_vector_type(4)));
typedef unsigned int u32;

// ---------------------------------------------------------------------------
// helpers
// ---------------------------------------------------------------------------
__device__ __forceinline__ void gload16(const void* g, void* l) {
  // async global->LDS, 16B/lane; LDS dest is wave-uniform base + lane*16
  __builtin_amdgcn_global_load_lds((const __attribute__((address_space(1))) u32*)g,
                                   (__attribute__((address_space(3))) u32*)l,
                                   16, 0, 0);
}

__device__ __forceinline__ void split2(float x, _Float16& h, _Float16& l) {
  _Float16 hi = (_Float16)x;
  h = hi;
  l = (_Float16)((x - (float)hi) * 2048.0f);  // lo scaled by 2^11 (avoid denormals)
}

__device__ __forceinline__ float blockMax(float v, float* sh) {
#pragma unroll
  for (int o = 32; o; o >>= 1) v = fmaxf(v, __shfl_xor(v, o));
  if ((threadIdx.x & 63) == 0) sh[threadIdx.x >> 6] = v;
  __syncthreads();
  float r = fmaxf(fmaxf(sh[0], sh[1]), fmaxf(sh[2], sh[3]));
  __syncthreads();
  return r;
}

__device__ __forceinline__ float blockSum(float v, float* sh) {
#pragma unroll
  for (int o = 32; o; o >>= 1) v += __shfl_xor(v, o);
  if ((threadIdx.x & 63) == 0) sh[threadIdx.x >> 6] = v;
  __syncthreads();
  float r = (sh[0] + sh[1]) + (sh[2] + sh[3]);
  __syncthreads();
  return r;
}

// max value, ties -> smallest index (replicates jnp.argmax first-occurrence)
__device__ __forceinline__ void blockArgmax(float& v, int& i, float* shf, int* shi) {
#pragma unroll
  for (int o = 32; o; o >>= 1) {
    float v2 = __shfl_xor(v, o);
    int   i2 = __shfl_xor(i, o);
    if (v2 > v || (v2 == v && i2 < i)) { v = v2; i = i2; }
  }
  if ((threadIdx.x & 63) == 0) { shf[threadIdx.x >> 6] = v; shi[threadIdx.x >> 6] = i; }
  __syncthreads();
  float bv = shf[0]; int bi = shi[0];
#pragma unroll
  for (int k = 1; k < 4; ++k) {
    float v2 = shf[k]; int i2 = shi[k];
    if (v2 > bv || (v2 == bv && i2 < bi)) { bv = v2; bi = i2; }
  }
  v = bv; i = bi;
  __syncthreads();
}

// ---------------------------------------------------------------------------
// elementwise split (fp32 -> fp16 hi + 2048*lo)
// ---------------------------------------------------------------------------
__global__ void split_kernel(const float* __restrict__ s, size_t n,
                             _Float16* __restrict__ h, _Float16* __restrict__ l) {
  size_t i = (size_t)blockIdx.x * blockDim.x + threadIdx.x;
  size_t st = (size_t)gridDim.x * blockDim.x;
  for (; i < n; i += st) {
    _Float16 hi, lo;
    split2(s[i], hi, lo);
    h[i] = hi; l[i] = lo;
  }
}

// transpose W[K][N] -> Wt[N][K] with split, via LDS tile (coalesced both sides)
__global__ void tsplit_kernel(const float* __restrict__ W, int K, int N,
                              _Float16* __restrict__ th, _Float16* __restrict__ tl) {
  __shared__ float tile[32][33];
  int nb = blockIdx.x * 32, kb = blockIdx.y * 32;
  int tx = threadIdx.x, ty = threadIdx.y;
  for (int r = ty; r < 32; r += 8)
    tile[r][tx] = W[(size_t)(kb + r) * N + nb + tx];
  __syncthreads();
  for (int r = ty; r < 32; r += 8) {
    float x = tile[tx][r];              // = W[kb+tx][nb+r]
    size_t o = (size_t)(nb + r) * K + kb + tx;
    _Float16 hi, lo; split2(x, hi, lo);
    th[o] = hi; tl[o] = lo;
  }
}

// per-row squared norms (4 waves/block, one row per wave)
__global__ void rownorm_kernel(const float* __restrict__ A, int rows, int K,
                               float* __restrict__ out) {
  int w = threadIdx.x >> 6, lane = threadIdx.x & 63;
  int row = blockIdx.x * 4 + w;
  if (row >= rows) return;
  const float* a = A + (size_t)row * K;
  float s = 0.f;
  for (int k = lane; k < K; k += 64) { float x = a[k]; s += x * x; }
#pragma unroll
  for (int o = 32; o; o >>= 1) s += __shfl_xor(s, o);
  if (lane == 0) out[row] = s;
}

// ---------------------------------------------------------------------------
// split-fp16 MFMA GEMM: C[m][n] = sum_k A[m][k] * Bmat[n][k]   (NT, both [.,K])
// A ~ Ah + Al/2048, B ~ Bh + Bl/2048; acc = hh;  accc = h*l + l*h (scale 2^11)
// 128x128 tile, BK=64, 4 waves; wave w stages LDS tile w (Ah/Al/Bh/Bl) via
// global_load_lds (16B) with XOR source-swizzle; reads undo the swizzle.
// (This engine verified: rounds 1/2/3 produced bit-identical results.)
// EPI 0: relu(c + bias-cat) -> split fp16 pair  (encoder layer 1, N=2048 cat)
// EPI 1: c + bias -> f32                        (encoder layer 2)
// EPI 2: 2c - rown[m] - coln[n] -> f32          (-||a-b||^2 logits)
// ---------------------------------------------------------------------------
template <int EPI>
__launch_bounds__(256, 2)
__global__ void gemm_split(const _Float16* __restrict__ Ah, const _Float16* __restrict__ Al,
                           const _Float16* __restrict__ Bh, const _Float16* __restrict__ Bl,
                           int N, int K, int lda, int ldc,
                           const float* __restrict__ bias, const float* __restrict__ bias2,
                           float* __restrict__ Cf,
                           _Float16* __restrict__ Ch, _Float16* __restrict__ Cl,
                           const float* __restrict__ rown, const float* __restrict__ coln) {
  __shared__ _Float16 lds[4 * 8192];  // 64 KiB: Ah | Al | Bh | Bl tiles [128][64]
  const int tid = threadIdx.x;
  const int w = tid >> 6, lane = tid & 63;
  const int m0 = blockIdx.y * 128, n0 = blockIdx.x * 128;
  const int g4 = lane >> 4, l15 = lane & 15;
  const int ln3 = lane >> 3, l7 = lane & 7;
  const int wsx = l7 ^ ln3;  // source-side XOR swizzle (16B units within 128B row)
  const int strideA = (w < 2) ? lda : K;
  const size_t laneoff = (size_t)ln3 * strideA + (size_t)wsx * 8;

  const _Float16* stage_src =
      (w == 0) ? (Ah + (size_t)m0 * lda) :
      (w == 1) ? (Al + (size_t)m0 * lda) :
      (w == 2) ? (Bh + (size_t)n0 * K) : (Bl + (size_t)n0 * K);
  _Float16* stage_dst = &lds[w * 8192];

  const int wm = w >> 1, wn = w & 1;  // wave quadrant (64x64)

  f32x4 acc[4][4] = {};
  f32x4 accc[4][4] = {};

  for (int k0 = 0; k0 < K; k0 += 64) {
    const _Float16* sp = stage_src + k0 + laneoff;
#pragma unroll
    for (int q = 0; q < 16; ++q)
      gload16(sp + (size_t)q * 8 * strideA, stage_dst + q * 512);
    __syncthreads();

#pragma unroll
    for (int kk = 0; kk < 2; ++kk) {
      half8 ah[4], al[4], bh[4], bl[4];
#pragma unroll
      for (int mi = 0; mi < 4; ++mi) {
        int row = wm * 64 + mi * 16 + l15;
        int off = row * 64 + (((kk * 4 + g4) ^ (l15 & 7)) * 8);
        ah[mi] = *(const half8*)&lds[off];
        al[mi] = *(const half8*)&lds[8192 + off];
      }
#pragma unroll
      for (int ni = 0; ni < 4; ++ni) {
        int row = wn * 64 + ni * 16 + l15;
        int off = row * 64 + (((kk * 4 + g4) ^ (l15 & 7)) * 8);
        bh[ni] = *(const half8*)&lds[16384 + off];
        bl[ni] = *(const half8*)&lds[24576 + off];
      }
#pragma unroll
      for (int mi = 0; mi < 4; ++mi)
#pragma unroll
        for (int ni = 0; ni < 4; ++ni) {
          acc[mi][ni]  = __builtin_amdgcn_mfma_f32_16x16x32_f16(ah[mi], bh[ni], acc[mi][ni], 0, 0, 0);
          accc[mi][ni] = __builtin_amdgcn_mfma_f32_16x16x32_f16(ah[mi], bl[ni], accc[mi][ni], 0, 0, 0);
          accc[mi][ni] = __builtin_amdgcn_mfma_f32_16x16x32_f16(al[mi], bh[ni], accc[mi][ni], 0, 0, 0);
        }
    }
    __syncthreads();
  }

#pragma unroll
  for (int mi = 0; mi < 4; ++mi)
#pragma unroll
    for (int ni = 0; ni < 4; ++ni)
#pragma unroll
      for (int r = 0; r < 4; ++r) {
        int m = m0 + wm * 64 + mi * 16 + g4 * 4 + r;
        int n = n0 + wn * 64 + ni * 16 + l15;
        float c = acc[mi][ni][r] + accc[mi][ni][r] * (1.0f / 2048.0f);
        size_t idx = (size_t)m * ldc + n;
        if (EPI == 0) {
          float bv = (n < H_) ? bias[n] : bias2[n - H_];
          c = fmaxf(c + bv, 0.0f);
          _Float16 hi, lo; split2(c, hi, lo);
          Ch[idx] = hi; Cl[idx] = lo;
        } else if (EPI == 1) {
          Cf[idx] = c + bias[n];
        } else {
          Cf[idx] = 2.0f * c - rown[m] - coln[n];
        }
      }
}

// ---------------------------------------------------------------------------
// Z = mu + softplus(ps)*eps ; writes mu,Z (fp32 out), Z split pair, ||Z||^2
// ---------------------------------------------------------------------------
__global__ __launch_bounds__(256) void kz_kernel(const float* __restrict__ mu,
                                                 const float* __restrict__ ps,
                                                 const float* __restrict__ eps,
                                                 float* __restrict__ out,
                                                 _Float16* __restrict__ Zh,
                                                 _Float16* __restrict__ Zl,
                                                 float* __restrict__ z2) {
  __shared__ float sh[4];
  int row = blockIdx.x, t = threadIdx.x;
  float s = 0.f;
  for (int j = t; j < D_; j += 256) {
    size_t idx = (size_t)row * D_ + j;
    float m = mu[idx], p = ps[idx], e = eps[idx];
    float sp = fmaxf(p, 0.f) + log1pf(expf(-fabsf(p)));  // stable softplus
    float z = m + sp * e;
    out[O_MU + idx] = m;
    out[O_Z + idx] = z;
    _Float16 hi, lo; split2(z, hi, lo);
    Zh[idx] = hi; Zl[idx] = lo;
    s += z * z;
  }
#pragma unroll
  for (int o = 32; o; o >>= 1) s += __shfl_xor(s, o);
  if ((t & 63) == 0) sh[t >> 6] = s;
  __syncthreads();
  if (t == 0) z2[row] = (sh[0] + sh[1]) + (sh[2] + sh[3]);
}

// ---------------------------------------------------------------------------
// fine routing: per-row double softmax + gumbel + argmax over S=4096
// logits buffer holds rows [row0, row0+gridDim); outputs indexed globally
// ---------------------------------------------------------------------------
__global__ __launch_bounds__(256) void ks_kernel(const float* __restrict__ logits,
                                                 const float* __restrict__ us,
                                                 float* __restrict__ out,
                                                 int* __restrict__ fidx, int row0) {
  __shared__ float shf[4];
  __shared__ int shi[4];
  int row = row0 + blockIdx.x, t = threadIdx.x;
  const float* l = logits + (size_t)blockIdx.x * S_;
  const float* u = us + (size_t)row * S_;

  float v[16];
  float m1 = -3.4e38f;
#pragma unroll
  for (int k = 0; k < 16; ++k) { v[k] = l[t + k * 256]; m1 = fmaxf(m1, v[k]); }
  m1 = blockMax(m1, shf);
  float s1 = 0.f;
#pragma unroll
  for (int k = 0; k < 16; ++k) { v[k] = expf(v[k] - m1); s1 += v[k]; }
  s1 = blockSum(s1, shf);
  float m2 = -3.4e38f;
#pragma unroll
  for (int k = 0; k < 16; ++k) {
    float p = v[k] / s1 + 1e-9f;                       // softmax + 1e-9
    float uu = u[t + k * 256];
    float g = -logf(-logf(uu + 1e-20f) + 1e-20f);      // gumbel noise
    v[k] = (logf(p) + g) * 2.0f;                       // (log p + g)/0.5
    m2 = fmaxf(m2, v[k]);
  }
  m2 = blockMax(m2, shf);
  float s2 = 0.f;
#pragma unroll
  for (int k = 0; k < 16; ++k) { v[k] = expf(v[k] - m2); s2 += v[k]; }
  s2 = blockSum(s2, shf);
  float bv = -3.4e38f; int bi = 0x7fffffff;
#pragma unroll
  for (int k = 0; k < 16; ++k) {
    float p = v[k] / s2;
    out[O_SOFT + (size_t)row * S_ + t + k * 256] = p;
    if (p > bv) { bv = p; bi = t + k * 256; }          // ascending j: > keeps first
  }
  blockArgmax(bv, bi, shf, shi);
#pragma unroll
  for (int k = 0; k < 16; ++k) {
    int j = t + k * 256;
    out[O_HARD + (size_t)row * S_ + j] = (j == bi) ? 1.0f : 0.0f;
  }
  if (t == 0) fidx[row] = bi;
}

// ---------------------------------------------------------------------------
// coarse routing: logits = 0.5*(lzy[row] + lsy[fine_idx]); gumbel; argmax
// ---------------------------------------------------------------------------
__global__ __launch_bounds__(256) void ky_kernel(const float* __restrict__ lzy,
                                                 const float* __restrict__ lsy,
                                                 const int* __restrict__ fidx,
                                                 const float* __restrict__ uy,
                                                 float* __restrict__ out) {
  __shared__ float shf[4];
  __shared__ int shi[4];
  int row = blockIdx.x, t = threadIdx.x;  // Y_ == 256 == blockDim
  int fi = fidx[row];
  float lc = 0.5f * (lzy[(size_t)row * Y_ + t] + lsy[(size_t)fi * Y_ + t]);
  float m1 = blockMax(lc, shf);
  float e = expf(lc - m1);
  float s1 = blockSum(e, shf);
  float p = e / s1 + 1e-9f;
  float g = -logf(-logf(uy[(size_t)row * Y_ + t] + 1e-20f) + 1e-20f);
  float a = (logf(p) + g) * 2.0f;
  float m2 = blockMax(a, shf);
  float y = expf(a - m2);
  float s2 = blockSum(y, shf);
  float sp = y / s2;
  out[O_SOFTY + (size_t)row * Y_ + t] = sp;
  float bv = sp; int bi = t;
  blockArgmax(bv, bi, shf, shi);
  if (t == 0) out[O_BY + row] = (float)bi;
}

// ---------------------------------------------------------------------------
// launch
// ---------------------------------------------------------------------------
extern "C" void kernel_launch(void* const* d_in, const int* in_sizes, int n_in,
                              void* d_out, int out_size, void* d_ws, size_t ws_size,
                              hipStream_t stream) {
  const float* X    = (const float*)d_in[0];
  const float* W1   = (const float*)d_in[1];
  const float* b1   = (const float*)d_in[2];
  const float* W2   = (const float*)d_in[3];
  const float* b2   = (const float*)d_in[4];
  const float* Ws1  = (const float*)d_in[5];
  const float* bs1  = (const float*)d_in[6];
  const float* Ws2  = (const float*)d_in[7];
  const float* bs2  = (const float*)d_in[8];
  const float* mu_y = (const float*)d_in[9];
  const float* mu_s = (const float*)d_in[10];
  const float* eps  = (const float*)d_in[11];
  const float* u_s  = (const float*)d_in[12];
  const float* u_y  = (const float*)d_in[13];
  float* out = (float*)d_out;   // OUTPUT dtype is FLOAT32

  // ---- workspace layout (peak 151.6 MB < 164 MB proven available) ----
  // Region A [0, 125.83 MB): encoder temporaries, all dead after kz.
  // Later reuse of A's span: LOG_HALF @0 (67.1MB), LZY @67.1MB, LSY @75.5MB.
  // Region B @125.83 MB: buffers live across dist GEMMs + routing.
  char* ws = (char*)d_ws;
  _Float16* XH    = (_Float16*)(ws + 0);            //  8,388,608
  _Float16* XL    = (_Float16*)(ws + 8388608);      //  8,388,608
  _Float16* W1CH  = (_Float16*)(ws + 16777216);     //  2,097,152  [2048][512] cat(W1T,Ws1T)
  _Float16* W1CL  = (_Float16*)(ws + 18874368);
  _Float16* W2TH  = (_Float16*)(ws + 20971520);     //  1,048,576  [512][1024]
  _Float16* W2TL  = (_Float16*)(ws + 22020096);
  _Float16* WS2TH = (_Float16*)(ws + 23068672);
  _Float16* WS2TL = (_Float16*)(ws + 24117248);
  _Float16* H1H   = (_Float16*)(ws + 25165824);     // 33,554,432  [8192][2048]
  _Float16* H1L   = (_Float16*)(ws + 58720256);
  float*    MUF   = (float*)  (ws + 92274688);      // 16,777,216
  float*    PSF   = (float*)  (ws + 109051904);     // ends 125,829,120
  // reuse of region A span (written only after region A dead):
  float*    LOGH  = (float*)  (ws + 0);             // 67,108,864  [4096][4096]
  float*    LZY   = (float*)  (ws + 67108864);      //  8,388,608
  float*    LSY   = (float*)  (ws + 75497472);      //  4,194,304
  // region B:
  const size_t RB = 125829120;
  _Float16* MSH  = (_Float16*)(ws + RB + 0);        //  4,194,304
  _Float16* MSL  = (_Float16*)(ws + RB + 4194304);
  _Float16* MYH  = (_Float16*)(ws + RB + 8388608);  //    262,144
  _Float16* MYL  = (_Float16*)(ws + RB + 8650752);
  _Float16* ZH   = (_Float16*)(ws + RB + 8912896);  //  8,388,608
  _Float16* ZL   = (_Float16*)(ws + RB + 17301504);
  float*    Z2   = (float*)  (ws + RB + 25690112);  //     32,768
  float*    CS2  = (float*)  (ws + RB + 25722880);  //     16,384
  float*    CY2  = (float*)  (ws + RB + 25739264);  //      4,096
  int*      FIDX = (int*)    (ws + RB + 25743360);  //     32,768 -> end 151,605,248
  (void)ws_size; (void)in_sizes; (void)n_in; (void)out_size;

  // 1) splits + transposes + norms
  split_kernel<<<2048, 256, 0, stream>>>(X, (size_t)B_ * D_, XH, XL);
  split_kernel<<<2048, 256, 0, stream>>>(mu_s, (size_t)S_ * D_, MSH, MSL);
  split_kernel<<<512, 256, 0, stream>>>(mu_y, (size_t)Y_ * D_, MYH, MYL);
  tsplit_kernel<<<dim3(H_ / 32, D_ / 32), dim3(32, 8), 0, stream>>>(W1, D_, H_, W1CH, W1CL);
  tsplit_kernel<<<dim3(H_ / 32, D_ / 32), dim3(32, 8), 0, stream>>>(Ws1, D_, H_,
      W1CH + (size_t)H_ * D_, W1CL + (size_t)H_ * D_);
  tsplit_kernel<<<dim3(D_ / 32, H_ / 32), dim3(32, 8), 0, stream>>>(W2, H_, D_, W2TH, W2TL);
  tsplit_kernel<<<dim3(D_ / 32, H_ / 32), dim3(32, 8), 0, stream>>>(Ws2, H_, D_, WS2TH, WS2TL);
  rownorm_kernel<<<S_ / 4, 256, 0, stream>>>(mu_s, S_, D_, CS2);
  rownorm_kernel<<<Y_ / 4, 256, 0, stream>>>(mu_y, Y_, D_, CY2);

  // 2) encoder layer 1 (fused: N = 2048 = cat(H1, S1)), relu+split epilogue
  gemm_split<0><<<dim3(2 * H_ / 128, B_ / 128), 256, 0, stream>>>(
      XH, XL, W1CH, W1CL, 2 * H_, D_, D_, 2 * H_,
      b1, bs1, nullptr, H1H, H1L, nullptr, nullptr);

  // 3) encoder layer 2 (A = column slices of H1 cat buffer, lda = 2048)
  gemm_split<1><<<dim3(D_ / 128, B_ / 128), 256, 0, stream>>>(
      H1H, H1L, W2TH, W2TL, D_, H_, 2 * H_, D_,
      b2, nullptr, MUF, nullptr, nullptr, nullptr, nullptr);
  gemm_split<1><<<dim3(D_ / 128, B_ / 128), 256, 0, stream>>>(
      H1H + H_, H1L + H_, WS2TH, WS2TL, D_, H_, 2 * H_, D_,
      bs2, nullptr, PSF, nullptr, nullptr, nullptr, nullptr);

  // 4) reparameterize (region A dead after this)
  kz_kernel<<<B_, 256, 0, stream>>>(MUF, PSF, eps, out, ZH, ZL, Z2);

  // 5) fine logits + routing, in two M=4096 halves sharing LOGH
  gemm_split<2><<<dim3(S_ / 128, 4096 / 128), 256, 0, stream>>>(
      ZH, ZL, MSH, MSL, S_, D_, D_, S_,
      nullptr, nullptr, LOGH, nullptr, nullptr, Z2, CS2);
  ks_kernel<<<4096, 256, 0, stream>>>(LOGH, u_s, out, FIDX, 0);
  gemm_split<2><<<dim3(S_ / 128, 4096 / 128), 256, 0, stream>>>(
      ZH + (size_t)4096 * D_, ZL + (size_t)4096 * D_, MSH, MSL, S_, D_, D_, S_,
      nullptr, nullptr, LOGH, nullptr, nullptr, Z2 + 4096, CS2);
  ks_kernel<<<4096, 256, 0, stream>>>(LOGH, u_s, out, FIDX, 4096);

  // 6) coarse logits + routing
  gemm_split<2><<<dim3(Y_ / 128, B_ / 128), 256, 0, stream>>>(
      ZH, ZL, MYH, MYL, Y_, D_, D_, Y_,
      nullptr, nullptr, LZY, nullptr, nullptr, Z2, CY2);
  gemm_split<2><<<dim3(Y_ / 128, S_ / 128), 256, 0, stream>>>(
      MSH, MSL, MYH, MYL, Y_, D_, D_, Y_,
      nullptr, nullptr, LSY, nullptr, nullptr, CS2, CY2);
  ky_kernel<<<B_, 256, 0, stream>>>(LZY, LSY, FIDX, u_y, out);
}

// Round 7
// 418.370 us; speedup vs baseline: 3.7971x; 1.0876x over previous
//
#include <hip/hip_runtime.h>
#include <hip/hip_bf16.h>

// Problem sizes (fixed by the reference)
#define B_ 8192
#define D_ 512
#define H_ 1024
#define S_ 4096
#define Y_ 256

// Output element offsets (fp32 elements) in return order:
// mu, Z, soft_prob, soft_prob_y, hard_prob, batch_y   (d_out is FLOAT32)
constexpr size_t O_MU    = 0;
constexpr size_t O_Z     = (size_t)B_ * D_;
constexpr size_t O_SOFT  = O_Z + (size_t)B_ * D_;
constexpr size_t O_SOFTY = O_SOFT + (size_t)B_ * S_;
constexpr size_t O_HARD  = O_SOFTY + (size_t)B_ * Y_;
constexpr size_t O_BY    = O_HARD + (size_t)B_ * S_;

typedef _Float16 half8 __attribute__((ext_vector_type(8)));
typedef float f32x4 __attribute__((ext_vector_type(4)));
typedef unsigned int u32;

// ---------------------------------------------------------------------------
// helpers
// ---------------------------------------------------------------------------
__device__ __forceinline__ void gload16(const void* g, void* l) {
  __builtin_amdgcn_global_load_lds((const __attribute__((address_space(1))) u32*)g,
                                   (__attribute__((address_space(3))) u32*)l,
                                   16, 0, 0);
}

__device__ __forceinline__ void split2(float x, _Float16& h, _Float16& l) {
  _Float16 hi = (_Float16)x;
  h = hi;
  l = (_Float16)((x - (float)hi) * 2048.0f);  // lo scaled by 2^11 (avoid denormals)
}

__device__ __forceinline__ float blockMax(float v, float* sh) {
#pragma unroll
  for (int o = 32; o; o >>= 1) v = fmaxf(v, __shfl_xor(v, o));
  if ((threadIdx.x & 63) == 0) sh[threadIdx.x >> 6] = v;
  __syncthreads();
  float r = fmaxf(fmaxf(sh[0], sh[1]), fmaxf(sh[2], sh[3]));
  __syncthreads();
  return r;
}

__device__ __forceinline__ float blockSum(float v, float* sh) {
#pragma unroll
  for (int o = 32; o; o >>= 1) v += __shfl_xor(v, o);
  if ((threadIdx.x & 63) == 0) sh[threadIdx.x >> 6] = v;
  __syncthreads();
  float r = (sh[0] + sh[1]) + (sh[2] + sh[3]);
  __syncthreads();
  return r;
}

// max value, ties -> smallest index (replicates jnp.argmax first-occurrence)
__device__ __forceinline__ void blockArgmax(float& v, int& i, float* shf, int* shi) {
#pragma unroll
  for (int o = 32; o; o >>= 1) {
    float v2 = __shfl_xor(v, o);
    int   i2 = __shfl_xor(i, o);
    if (v2 > v || (v2 == v && i2 < i)) { v = v2; i = i2; }
  }
  if ((threadIdx.x & 63) == 0) { shf[threadIdx.x >> 6] = v; shi[threadIdx.x >> 6] = i; }
  __syncthreads();
  float bv = shf[0]; int bi = shi[0];
#pragma unroll
  for (int k = 1; k < 4; ++k) {
    float v2 = shf[k]; int i2 = shi[k];
    if (v2 > bv || (v2 == bv && i2 < bi)) { bv = v2; bi = i2; }
  }
  v = bv; i = bi;
  __syncthreads();
}

// ---------------------------------------------------------------------------
// fused prep: splits (X, mu_s, mu_y), transpose-splits (W1|Ws1 cat, W2|Ws2 cat),
// row norms (mu_s, mu_y) — one dispatch, block-range dispatching.
// ---------------------------------------------------------------------------
__device__ void seg_split(const float* __restrict__ s, _Float16* __restrict__ h,
                          _Float16* __restrict__ l, size_t n, int b, int nb) {
  size_t i = (size_t)b * 256 + threadIdx.x;
  size_t st = (size_t)nb * 256;
  for (; i < n; i += st) { _Float16 hi, lo; split2(s[i], hi, lo); h[i] = hi; l[i] = lo; }
}

__device__ void seg_tsplit(const float* __restrict__ W, int K, int N,
                           _Float16* __restrict__ th, _Float16* __restrict__ tl,
                           int tile, float (*tl_lds)[33]) {
  int ntn = N / 32;
  int nb = (tile % ntn) * 32, kb = (tile / ntn) * 32;
  int tx = threadIdx.x & 31, ty = threadIdx.x >> 5;  // 32 x 8
  for (int r = ty; r < 32; r += 8)
    tl_lds[r][tx] = W[(size_t)(kb + r) * N + nb + tx];
  __syncthreads();
  for (int r = ty; r < 32; r += 8) {
    float x = tl_lds[tx][r];            // = W[kb+tx][nb+r]
    size_t o = (size_t)(nb + r) * K + kb + tx;
    _Float16 hi, lo; split2(x, hi, lo);
    th[o] = hi; tl[o] = lo;
  }
}

__device__ void seg_rownorm(const float* __restrict__ A, int K, float* __restrict__ out,
                            int tile) {
  int w = threadIdx.x >> 6, lane = threadIdx.x & 63;
  int row = tile * 4 + w;
  const float* a = A + (size_t)row * K;
  float s = 0.f;
  for (int k = lane; k < K; k += 64) { float x = a[k]; s += x * x; }
#pragma unroll
  for (int o = 32; o; o >>= 1) s += __shfl_xor(s, o);
  if (lane == 0) out[row] = s;
}

__global__ __launch_bounds__(256) void prep_kernel(
    const float* __restrict__ X, const float* __restrict__ W1, const float* __restrict__ Ws1,
    const float* __restrict__ W2, const float* __restrict__ Ws2,
    const float* __restrict__ mu_s, const float* __restrict__ mu_y,
    _Float16* XH, _Float16* XL, _Float16* MSH, _Float16* MSL,
    _Float16* MYH, _Float16* MYL,
    _Float16* W1CH, _Float16* W1CL, _Float16* W2CH, _Float16* W2CL,
    float* CS2, float* CY2) {
  __shared__ float tile[32][33];
  int b = blockIdx.x;  // all threads of a block take the same branch
  if (b < 512)       seg_split(X,    XH,  XL,  (size_t)B_ * D_, b,        512);
  else if (b < 768)  seg_split(mu_s, MSH, MSL, (size_t)S_ * D_, b - 512,  256);
  else if (b < 784)  seg_split(mu_y, MYH, MYL, (size_t)Y_ * D_, b - 768,  16);
  else if (b < 1296) seg_tsplit(W1,  D_, H_, W1CH, W1CL, b - 784, tile);
  else if (b < 1808) seg_tsplit(Ws1, D_, H_, W1CH + (size_t)H_ * D_,
                                W1CL + (size_t)H_ * D_, b - 1296, tile);
  else if (b < 2320) seg_tsplit(W2,  H_, D_, W2CH, W2CL, b - 1808, tile);
  else if (b < 2832) seg_tsplit(Ws2, H_, D_, W2CH + (size_t)D_ * H_,
                                W2CL + (size_t)D_ * H_, b - 2320, tile);
  else if (b < 3856) seg_rownorm(mu_s, D_, CS2, b - 2832);
  else               seg_rownorm(mu_y, D_, CY2, b - 3856);
}

// ---------------------------------------------------------------------------
// split-fp16 MFMA GEMM: C[m][n] = sum_k A[m][k] * Bmat[n][k]   (NT, both [.,K])
// A ~ Ah + Al/2048, B ~ Bh + Bl/2048; acc = hh;  accc = h*l + l*h (scale 2^11)
// 128x128 tile, BK=64, 4 waves; wave w stages LDS tile w (Ah/Al/Bh/Bl) via
// global_load_lds (16B) with XOR source-swizzle; reads undo the swizzle.
// nsplit: column where bias/bias2 switch (EPI 0/1); aoff2: A column offset
// applied for blocks with n0 >= nsplit (fused L2: mu-head vs sigma-head).
// EPI 0: relu(c + cat-bias) -> split fp16 pair
// EPI 1: c + cat-bias -> f32
// EPI 2: 2c - rown[m] - coln[n] -> f32          (-||a-b||^2 logits)
// ---------------------------------------------------------------------------
template <int EPI>
__launch_bounds__(256, 2)
__global__ void gemm_split(const _Float16* __restrict__ Ah, const _Float16* __restrict__ Al,
                           const _Float16* __restrict__ Bh, const _Float16* __restrict__ Bl,
                           int N, int K, int lda, int ldc, int nsplit, int aoff2,
                           const float* __restrict__ bias, const float* __restrict__ bias2,
                           float* __restrict__ Cf,
                           _Float16* __restrict__ Ch, _Float16* __restrict__ Cl,
                           const float* __restrict__ rown, const float* __restrict__ coln) {
  __shared__ _Float16 lds[4 * 8192];  // 64 KiB: Ah | Al | Bh | Bl tiles [128][64]
  const int tid = threadIdx.x;
  const int w = tid >> 6, lane = tid & 63;
  const int m0 = blockIdx.y * 128, n0 = blockIdx.x * 128;
  const int g4 = lane >> 4, l15 = lane & 15;
  const int ln3 = lane >> 3, l7 = lane & 7;
  const int wsx = l7 ^ ln3;  // source-side XOR swizzle (16B units within 128B row)
  const int strideA = (w < 2) ? lda : K;
  const size_t laneoff = (size_t)ln3 * strideA + (size_t)wsx * 8;
  const int ashift = (n0 >= nsplit) ? aoff2 : 0;  // block-uniform

  const _Float16* stage_src =
      (w == 0) ? (Ah + (size_t)m0 * lda + ashift) :
      (w == 1) ? (Al + (size_t)m0 * lda + ashift) :
      (w == 2) ? (Bh + (size_t)n0 * K) : (Bl + (size_t)n0 * K);
  _Float16* stage_dst = &lds[w * 8192];

  const int wm = w >> 1, wn = w & 1;  // wave quadrant (64x64)

  f32x4 acc[4][4] = {};
  f32x4 accc[4][4] = {};

  for (int k0 = 0; k0 < K; k0 += 64) {
    const _Float16* sp = stage_src + k0 + laneoff;
#pragma unroll
    for (int q = 0; q < 16; ++q)
      gload16(sp + (size_t)q * 8 * strideA, stage_dst + q * 512);
    __syncthreads();

#pragma unroll
    for (int kk = 0; kk < 2; ++kk) {
      half8 ah[4], al[4], bh[4], bl[4];
#pragma unroll
      for (int mi = 0; mi < 4; ++mi) {
        int row = wm * 64 + mi * 16 + l15;
        int off = row * 64 + (((kk * 4 + g4) ^ (l15 & 7)) * 8);
        ah[mi] = *(const half8*)&lds[off];
        al[mi] = *(const half8*)&lds[8192 + off];
      }
#pragma unroll
      for (int ni = 0; ni < 4; ++ni) {
        int row = wn * 64 + ni * 16 + l15;
        int off = row * 64 + (((kk * 4 + g4) ^ (l15 & 7)) * 8);
        bh[ni] = *(const half8*)&lds[16384 + off];
        bl[ni] = *(const half8*)&lds[24576 + off];
      }
#pragma unroll
      for (int mi = 0; mi < 4; ++mi)
#pragma unroll
        for (int ni = 0; ni < 4; ++ni) {
          acc[mi][ni]  = __builtin_amdgcn_mfma_f32_16x16x32_f16(ah[mi], bh[ni], acc[mi][ni], 0, 0, 0);
          accc[mi][ni] = __builtin_amdgcn_mfma_f32_16x16x32_f16(ah[mi], bl[ni], accc[mi][ni], 0, 0, 0);
          accc[mi][ni] = __builtin_amdgcn_mfma_f32_16x16x32_f16(al[mi], bh[ni], accc[mi][ni], 0, 0, 0);
        }
    }
    __syncthreads();
  }

#pragma unroll
  for (int mi = 0; mi < 4; ++mi)
#pragma unroll
    for (int ni = 0; ni < 4; ++ni)
#pragma unroll
      for (int r = 0; r < 4; ++r) {
        int m = m0 + wm * 64 + mi * 16 + g4 * 4 + r;
        int n = n0 + wn * 64 + ni * 16 + l15;
        float c = acc[mi][ni][r] + accc[mi][ni][r] * (1.0f / 2048.0f);
        size_t idx = (size_t)m * ldc + n;
        if (EPI == 0) {
          float bv = (n < nsplit) ? bias[n] : bias2[n - nsplit];
          c = fmaxf(c + bv, 0.0f);
          _Float16 hi, lo; split2(c, hi, lo);
          Ch[idx] = hi; Cl[idx] = lo;
        } else if (EPI == 1) {
          float bv = (n < nsplit) ? bias[n] : bias2[n - nsplit];
          Cf[idx] = c + bv;
        } else {
          Cf[idx] = 2.0f * c - rown[m] - coln[n];
        }
      }
}

// ---------------------------------------------------------------------------
// Z = mu + softplus(ps)*eps ; MPS holds [mu | ps] per row (ld 1024).
// writes mu,Z (fp32 out), Z split pair, ||Z||^2
// ---------------------------------------------------------------------------
__global__ __launch_bounds__(256) void kz_kernel(const float* __restrict__ MPS,
                                                 const float* __restrict__ eps,
                                                 float* __restrict__ out,
                                                 _Float16* __restrict__ Zh,
                                                 _Float16* __restrict__ Zl,
                                                 float* __restrict__ z2) {
  __shared__ float sh[4];
  int row = blockIdx.x, t = threadIdx.x;
  float s = 0.f;
  for (int j = t; j < D_; j += 256) {
    size_t idx = (size_t)row * D_ + j;
    float m = MPS[(size_t)row * 1024 + j];
    float p = MPS[(size_t)row * 1024 + 512 + j];
    float e = eps[idx];
    float sp = fmaxf(p, 0.f) + log1pf(expf(-fabsf(p)));  // stable softplus
    float z = m + sp * e;
    out[O_MU + idx] = m;
    out[O_Z + idx] = z;
    _Float16 hi, lo; split2(z, hi, lo);
    Zh[idx] = hi; Zl[idx] = lo;
    s += z * z;
  }
#pragma unroll
  for (int o = 32; o; o >>= 1) s += __shfl_xor(s, o);
  if ((t & 63) == 0) sh[t >> 6] = s;
  __syncthreads();
  if (t == 0) z2[row] = (sh[0] + sh[1]) + (sh[2] + sh[3]);
}

// ---------------------------------------------------------------------------
// fine routing: per-row double softmax + gumbel + argmax over S=4096.
// thread t owns 16 contiguous elements (float4 IO); exact first-index ties.
// ---------------------------------------------------------------------------
__global__ __launch_bounds__(256) void ks_kernel(const float* __restrict__ logits,
                                                 const float* __restrict__ us,
                                                 float* __restrict__ out,
                                                 int* __restrict__ fidx, int row0) {
  __shared__ float shf[4];
  __shared__ int shi[4];
  int row = row0 + blockIdx.x, t = threadIdx.x;
  const float4* l4 = (const float4*)(logits + (size_t)blockIdx.x * S_) + t * 4;
  const float4* u4 = (const float4*)(us + (size_t)row * S_) + t * 4;

  float v[16];
#pragma unroll
  for (int q = 0; q < 4; ++q) {
    float4 x = l4[q];
    v[q * 4 + 0] = x.x; v[q * 4 + 1] = x.y; v[q * 4 + 2] = x.z; v[q * 4 + 3] = x.w;
  }
  float m1 = -3.4e38f;
#pragma unroll
  for (int k = 0; k < 16; ++k) m1 = fmaxf(m1, v[k]);
  m1 = blockMax(m1, shf);
  float s1 = 0.f;
#pragma unroll
  for (int k = 0; k < 16; ++k) { v[k] = __expf(v[k] - m1); s1 += v[k]; }
  s1 = blockSum(s1, shf);
  float is1 = 1.0f / s1;
  float m2 = -3.4e38f;
#pragma unroll
  for (int q = 0; q < 4; ++q) {
    float4 uu = u4[q];
    float ua[4] = {uu.x, uu.y, uu.z, uu.w};
#pragma unroll
    for (int e = 0; e < 4; ++e) {
      int k = q * 4 + e;
      float p = v[k] * is1 + 1e-9f;                    // softmax + 1e-9
      float g = -logf(-logf(ua[e] + 1e-20f) + 1e-20f); // gumbel (precise logs)
      v[k] = (logf(p) + g) * 2.0f;                     // (log p + g)/0.5
      m2 = fmaxf(m2, v[k]);
    }
  }
  m2 = blockMax(m2, shf);
  float s2 = 0.f;
#pragma unroll
  for (int k = 0; k < 16; ++k) { v[k] = __expf(v[k] - m2); s2 += v[k]; }
  s2 = blockSum(s2, shf);
  float is2 = 1.0f / s2;
  float bv = -3.4e38f; int bi = 0x7fffffff;
  float* so = out + O_SOFT + (size_t)row * S_ + (size_t)t * 16;
#pragma unroll
  for (int q = 0; q < 4; ++q) {
    float pe[4];
#pragma unroll
    for (int e = 0; e < 4; ++e) {
      int k = q * 4 + e;
      pe[e] = v[k] * is2;
      if (pe[e] > bv) { bv = pe[e]; bi = t * 16 + k; } // ascending j: > keeps first
    }
    float4 pv; pv.x = pe[0]; pv.y = pe[1]; pv.z = pe[2]; pv.w = pe[3];
    ((float4*)so)[q] = pv;
  }
  blockArgmax(bv, bi, shf, shi);
  float* ho = out + O_HARD + (size_t)row * S_ + (size_t)t * 16;
#pragma unroll
  for (int q = 0; q < 4; ++q) {
    float4 hv;
    hv.x = (t * 16 + q * 4 + 0 == bi) ? 1.f : 0.f;
    hv.y = (t * 16 + q * 4 + 1 == bi) ? 1.f : 0.f;
    hv.z = (t * 16 + q * 4 + 2 == bi) ? 1.f : 0.f;
    hv.w = (t * 16 + q * 4 + 3 == bi) ? 1.f : 0.f;
    ((float4*)ho)[q] = hv;
  }
  if (t == 0) fidx[row] = bi;
}

// ---------------------------------------------------------------------------
// coarse routing: logits = 0.5*(lzy[row] + lsy[fine_idx]); gumbel; argmax
// ---------------------------------------------------------------------------
__global__ __launch_bounds__(256) void ky_kernel(const float* __restrict__ lzy,
                                                 const float* __restrict__ lsy,
                                                 const int* __restrict__ fidx,
                                                 const float* __restrict__ uy,
                                                 float* __restrict__ out) {
  __shared__ float shf[4];
  __shared__ int shi[4];
  int row = blockIdx.x, t = threadIdx.x;  // Y_ == 256 == blockDim
  int fi = fidx[row];
  float lc = 0.5f * (lzy[(size_t)row * Y_ + t] + lsy[(size_t)fi * Y_ + t]);
  float m1 = blockMax(lc, shf);
  float e = __expf(lc - m1);
  float s1 = blockSum(e, shf);
  float p = e / s1 + 1e-9f;
  float g = -logf(-logf(uy[(size_t)row * Y_ + t] + 1e-20f) + 1e-20f);
  float a = (logf(p) + g) * 2.0f;
  float m2 = blockMax(a, shf);
  float y = __expf(a - m2);
  float s2 = blockSum(y, shf);
  float sp = y / s2;
  out[O_SOFTY + (size_t)row * Y_ + t] = sp;
  float bv = sp; int bi = t;
  blockArgmax(bv, bi, shf, shi);
  if (t == 0) out[O_BY + row] = (float)bi;
}

// ---------------------------------------------------------------------------
// launch
// ---------------------------------------------------------------------------
extern "C" void kernel_launch(void* const* d_in, const int* in_sizes, int n_in,
                              void* d_out, int out_size, void* d_ws, size_t ws_size,
                              hipStream_t stream) {
  const float* X    = (const float*)d_in[0];
  const float* W1   = (const float*)d_in[1];
  const float* b1   = (const float*)d_in[2];
  const float* W2   = (const float*)d_in[3];
  const float* b2   = (const float*)d_in[4];
  const float* Ws1  = (const float*)d_in[5];
  const float* bs1  = (const float*)d_in[6];
  const float* Ws2  = (const float*)d_in[7];
  const float* bs2  = (const float*)d_in[8];
  const float* mu_y = (const float*)d_in[9];
  const float* mu_s = (const float*)d_in[10];
  const float* eps  = (const float*)d_in[11];
  const float* u_s  = (const float*)d_in[12];
  const float* u_y  = (const float*)d_in[13];
  float* out = (float*)d_out;   // OUTPUT dtype is FLOAT32

  // ---- workspace layout (peak 151.6 MB; ws >= 164 MB verified in R4) ----
  // Region A [0, 125.83 MB): encoder temporaries, all dead after kz.
  // Reuse of A's span after kz: LOGH@0, LZY@67.1M, LSY@75.5M.
  char* ws = (char*)d_ws;
  _Float16* XH    = (_Float16*)(ws + 0);            //  8,388,608
  _Float16* XL    = (_Float16*)(ws + 8388608);
  _Float16* W1CH  = (_Float16*)(ws + 16777216);     //  2,097,152  [2048][512] cat(W1T,Ws1T)
  _Float16* W1CL  = (_Float16*)(ws + 18874368);
  _Float16* W2CH  = (_Float16*)(ws + 20971520);     //  2,097,152  [1024][1024] cat(W2T,Ws2T)
  _Float16* W2CL  = (_Float16*)(ws + 23068672);
  _Float16* H1H   = (_Float16*)(ws + 25165824);     // 33,554,432  [8192][2048]
  _Float16* H1L   = (_Float16*)(ws + 58720256);
  float*    MPS   = (float*)  (ws + 92274688);      // 33,554,432  [8192][1024] = [mu|ps]
  // reuse of region A span (written only after region A dead):
  float*    LOGH  = (float*)  (ws + 0);             // 67,108,864  [4096][4096]
  float*    LZY   = (float*)  (ws + 67108864);      //  8,388,608
  float*    LSY   = (float*)  (ws + 75497472);      //  4,194,304
  // region B:
  const size_t RB = 125829120;
  _Float16* MSH  = (_Float16*)(ws + RB + 0);        //  4,194,304
  _Float16* MSL  = (_Float16*)(ws + RB + 4194304);
  _Float16* MYH  = (_Float16*)(ws + RB + 8388608);  //    262,144
  _Float16* MYL  = (_Float16*)(ws + RB + 8650752);
  _Float16* ZH   = (_Float16*)(ws + RB + 8912896);  //  8,388,608
  _Float16* ZL   = (_Float16*)(ws + RB + 17301504);
  float*    Z2   = (float*)  (ws + RB + 25690112);  //     32,768
  float*    CS2  = (float*)  (ws + RB + 25722880);  //     16,384
  float*    CY2  = (float*)  (ws + RB + 25739264);  //      4,096
  int*      FIDX = (int*)    (ws + RB + 25743360);  //     32,768 -> end 151,605,248
  (void)ws_size; (void)in_sizes; (void)n_in; (void)out_size;

  // 1) fused prep (splits + transpose-splits + codebook norms) — one dispatch
  prep_kernel<<<3920, 256, 0, stream>>>(X, W1, Ws1, W2, Ws2, mu_s, mu_y,
                                        XH, XL, MSH, MSL, MYH, MYL,
                                        W1CH, W1CL, W2CH, W2CL, CS2, CY2);

  // 2) encoder layer 1 (fused heads: N = 2048 = cat(H1, S1)), relu+split epi
  gemm_split<0><<<dim3(2 * H_ / 128, B_ / 128), 256, 0, stream>>>(
      XH, XL, W1CH, W1CL, 2 * H_, D_, D_, 2 * H_, H_, 0,
      b1, bs1, nullptr, H1H, H1L, nullptr, nullptr);

  // 3) encoder layer 2 (fused heads: N = 1024 = cat(mu, ps); A-col switch at 512)
  gemm_split<1><<<dim3(2 * D_ / 128, B_ / 128), 256, 0, stream>>>(
      H1H, H1L, W2CH, W2CL, 2 * D_, H_, 2 * H_, 2 * D_, D_, H_,
      b2, bs2, MPS, nullptr, nullptr, nullptr, nullptr);

  // 4) reparameterize (region A dead after this)
  kz_kernel<<<B_, 256, 0, stream>>>(MPS, eps, out, ZH, ZL, Z2);

  // 5) fine logits + routing, in two M=4096 halves sharing LOGH
  gemm_split<2><<<dim3(S_ / 128, 4096 / 128), 256, 0, stream>>>(
      ZH, ZL, MSH, MSL, S_, D_, D_, S_, S_, 0,
      nullptr, nullptr, LOGH, nullptr, nullptr, Z2, CS2);
  ks_kernel<<<4096, 256, 0, stream>>>(LOGH, u_s, out, FIDX, 0);
  gemm_split<2><<<dim3(S_ / 128, 4096 / 128), 256, 0, stream>>>(
      ZH + (size_t)4096 * D_, ZL + (size_t)4096 * D_, MSH, MSL, S_, D_, D_, S_, S_, 0,
      nullptr, nullptr, LOGH, nullptr, nullptr, Z2 + 4096, CS2);
  ks_kernel<<<4096, 256, 0, stream>>>(LOGH, u_s, out, FIDX, 4096);

  // 6) coarse logits + routing
  gemm_split<2><<<dim3(Y_ / 128, B_ / 128), 256, 0, stream>>>(
      ZH, ZL, MYH, MYL, Y_, D_, D_, Y_, Y_, 0,
      nullptr, nullptr, LZY, nullptr, nullptr, Z2, CY2);
  gemm_split<2><<<dim3(Y_ / 128, S_ / 128), 256, 0, stream>>>(
      MSH, MSL, MYH, MYL, Y_, D_, D_, Y_, Y_, 0,
      nullptr, nullptr, LSY, nullptr, nullptr, CS2, CY2);
  ky_kernel<<<B_, 256, 0, stream>>>(LZY, LSY, FIDX, u_y, out);
}

// Round 8
// 376.908 us; speedup vs baseline: 4.2148x; 1.1100x over previous
//
#include <hip/hip_runtime.h>
#include <hip/hip_bf16.h>

// Problem sizes (fixed by the reference)
#define B_ 8192
#define D_ 512
#define H_ 1024
#define S_ 4096
#define Y_ 256

// Output element offsets (fp32 elements) in return order:
// mu, Z, soft_prob, soft_prob_y, hard_prob, batch_y   (d_out is FLOAT32)
constexpr size_t O_MU    = 0;
constexpr size_t O_Z     = (size_t)B_ * D_;
constexpr size_t O_SOFT  = O_Z + (size_t)B_ * D_;
constexpr size_t O_SOFTY = O_SOFT + (size_t)B_ * S_;
constexpr size_t O_HARD  = O_SOFTY + (size_t)B_ * Y_;
constexpr size_t O_BY    = O_HARD + (size_t)B_ * S_;

typedef _Float16 half8 __attribute__((ext_vector_type(8)));
typedef float f32x4 __attribute__((ext_vector_type(4)));
typedef unsigned int u32;

// ---------------------------------------------------------------------------
// helpers
// ---------------------------------------------------------------------------
__device__ __forceinline__ void gload16(const void* g, void* l) {
  __builtin_amdgcn_global_load_lds((const __attribute__((address_space(1))) u32*)g,
                                   (__attribute__((address_space(3))) u32*)l,
                                   16, 0, 0);
}

__device__ __forceinline__ void split2(float x, _Float16& h, _Float16& l) {
  _Float16 hi = (_Float16)x;
  h = hi;
  l = (_Float16)((x - (float)hi) * 2048.0f);  // lo scaled by 2^11 (avoid denormals)
}

__device__ __forceinline__ float blockMax(float v, float* sh) {
#pragma unroll
  for (int o = 32; o; o >>= 1) v = fmaxf(v, __shfl_xor(v, o));
  if ((threadIdx.x & 63) == 0) sh[threadIdx.x >> 6] = v;
  __syncthreads();
  float r = fmaxf(fmaxf(sh[0], sh[1]), fmaxf(sh[2], sh[3]));
  __syncthreads();
  return r;
}

__device__ __forceinline__ float blockSum(float v, float* sh) {
#pragma unroll
  for (int o = 32; o; o >>= 1) v += __shfl_xor(v, o);
  if ((threadIdx.x & 63) == 0) sh[threadIdx.x >> 6] = v;
  __syncthreads();
  float r = (sh[0] + sh[1]) + (sh[2] + sh[3]);
  __syncthreads();
  return r;
}

// max value, ties -> smallest index (replicates jnp.argmax first-occurrence)
__device__ __forceinline__ void blockArgmax(float& v, int& i, float* shf, int* shi) {
#pragma unroll
  for (int o = 32; o; o >>= 1) {
    float v2 = __shfl_xor(v, o);
    int   i2 = __shfl_xor(i, o);
    if (v2 > v || (v2 == v && i2 < i)) { v = v2; i = i2; }
  }
  if ((threadIdx.x & 63) == 0) { shf[threadIdx.x >> 6] = v; shi[threadIdx.x >> 6] = i; }
  __syncthreads();
  float bv = shf[0]; int bi = shi[0];
#pragma unroll
  for (int k = 1; k < 4; ++k) {
    float v2 = shf[k]; int i2 = shi[k];
    if (v2 > bv || (v2 == bv && i2 < bi)) { bv = v2; bi = i2; }
  }
  v = bv; i = bi;
  __syncthreads();
}

// ---------------------------------------------------------------------------
// fused prep: splits (X, mu_s, mu_y), transpose-splits (W1|Ws1 cat, W2|Ws2 cat),
// row norms (mu_s, mu_y) — one dispatch, block-range dispatching.
// ---------------------------------------------------------------------------
__device__ void seg_split(const float* __restrict__ s, _Float16* __restrict__ h,
                          _Float16* __restrict__ l, size_t n, int b, int nb) {
  size_t i = (size_t)b * 256 + threadIdx.x;
  size_t st = (size_t)nb * 256;
  for (; i < n; i += st) { _Float16 hi, lo; split2(s[i], hi, lo); h[i] = hi; l[i] = lo; }
}

__device__ void seg_tsplit(const float* __restrict__ W, int K, int N,
                           _Float16* __restrict__ th, _Float16* __restrict__ tl,
                           int tile, float (*tl_lds)[33]) {
  int ntn = N / 32;
  int nb = (tile % ntn) * 32, kb = (tile / ntn) * 32;
  int tx = threadIdx.x & 31, ty = threadIdx.x >> 5;  // 32 x 8
  for (int r = ty; r < 32; r += 8)
    tl_lds[r][tx] = W[(size_t)(kb + r) * N + nb + tx];
  __syncthreads();
  for (int r = ty; r < 32; r += 8) {
    float x = tl_lds[tx][r];            // = W[kb+tx][nb+r]
    size_t o = (size_t)(nb + r) * K + kb + tx;
    _Float16 hi, lo; split2(x, hi, lo);
    th[o] = hi; tl[o] = lo;
  }
}

__device__ void seg_rownorm(const float* __restrict__ A, int K, float* __restrict__ out,
                            int tile) {
  int w = threadIdx.x >> 6, lane = threadIdx.x & 63;
  int row = tile * 4 + w;
  const float* a = A + (size_t)row * K;
  float s = 0.f;
  for (int k = lane; k < K; k += 64) { float x = a[k]; s += x * x; }
#pragma unroll
  for (int o = 32; o; o >>= 1) s += __shfl_xor(s, o);
  if (lane == 0) out[row] = s;
}

__global__ __launch_bounds__(256) void prep_kernel(
    const float* __restrict__ X, const float* __restrict__ W1, const float* __restrict__ Ws1,
    const float* __restrict__ W2, const float* __restrict__ Ws2,
    const float* __restrict__ mu_s, const float* __restrict__ mu_y,
    _Float16* XH, _Float16* XL, _Float16* MSH, _Float16* MSL,
    _Float16* MYH, _Float16* MYL,
    _Float16* W1CH, _Float16* W1CL, _Float16* W2CH, _Float16* W2CL,
    float* CS2, float* CY2) {
  __shared__ float tile[32][33];
  int b = blockIdx.x;  // all threads of a block take the same branch
  if (b < 512)       seg_split(X,    XH,  XL,  (size_t)B_ * D_, b,        512);
  else if (b < 768)  seg_split(mu_s, MSH, MSL, (size_t)S_ * D_, b - 512,  256);
  else if (b < 784)  seg_split(mu_y, MYH, MYL, (size_t)Y_ * D_, b - 768,  16);
  else if (b < 1296) seg_tsplit(W1,  D_, H_, W1CH, W1CL, b - 784, tile);
  else if (b < 1808) seg_tsplit(Ws1, D_, H_, W1CH + (size_t)H_ * D_,
                                W1CL + (size_t)H_ * D_, b - 1296, tile);
  else if (b < 2320) seg_tsplit(W2,  H_, D_, W2CH, W2CL, b - 1808, tile);
  else if (b < 2832) seg_tsplit(Ws2, H_, D_, W2CH + (size_t)D_ * H_,
                                W2CL + (size_t)D_ * H_, b - 2320, tile);
  else if (b < 3856) seg_rownorm(mu_s, D_, CS2, b - 2832);
  else               seg_rownorm(mu_y, D_, CY2, b - 3856);
}

// ---------------------------------------------------------------------------
// split-fp16 MFMA GEMM: C[m][n] = sum_k A[m][k] * Bmat[n][k]   (NT, both [.,K])
// A ~ Ah + Al/2048, B ~ Bh + Bl/2048; acc = hh;  accc = h*l + l*h (scale 2^11)
// 128x128 tile, BK=64, 4 waves; wave w stages LDS tile w (Ah/Al/Bh/Bl) via
// global_load_lds (16B) with XOR source-swizzle; reads undo the swizzle.
// nsplit: column where bias/bias2 switch (EPI 0/1); aoff2: A column offset
// applied for blocks with n0 >= nsplit (fused L2: mu-head vs sigma-head).
// EPI 0: relu(c + cat-bias) -> split fp16 pair
// EPI 1: c + cat-bias -> f32
// EPI 2: 2c - rown[m] - coln[n] -> f32          (-||a-b||^2 logits)
// ---------------------------------------------------------------------------
template <int EPI>
__launch_bounds__(256, 2)
__global__ void gemm_split(const _Float16* __restrict__ Ah, const _Float16* __restrict__ Al,
                           const _Float16* __restrict__ Bh, const _Float16* __restrict__ Bl,
                           int N, int K, int lda, int ldc, int nsplit, int aoff2,
                           const float* __restrict__ bias, const float* __restrict__ bias2,
                           float* __restrict__ Cf,
                           _Float16* __restrict__ Ch, _Float16* __restrict__ Cl,
                           const float* __restrict__ rown, const float* __restrict__ coln) {
  __shared__ _Float16 lds[4 * 8192];  // 64 KiB: Ah | Al | Bh | Bl tiles [128][64]
  const int tid = threadIdx.x;
  const int w = tid >> 6, lane = tid & 63;
  const int m0 = blockIdx.y * 128, n0 = blockIdx.x * 128;
  const int g4 = lane >> 4, l15 = lane & 15;
  const int ln3 = lane >> 3, l7 = lane & 7;
  const int wsx = l7 ^ ln3;  // source-side XOR swizzle (16B units within 128B row)
  const int strideA = (w < 2) ? lda : K;
  const size_t laneoff = (size_t)ln3 * strideA + (size_t)wsx * 8;
  const int ashift = (n0 >= nsplit) ? aoff2 : 0;  // block-uniform

  const _Float16* stage_src =
      (w == 0) ? (Ah + (size_t)m0 * lda + ashift) :
      (w == 1) ? (Al + (size_t)m0 * lda + ashift) :
      (w == 2) ? (Bh + (size_t)n0 * K) : (Bl + (size_t)n0 * K);
  _Float16* stage_dst = &lds[w * 8192];

  const int wm = w >> 1, wn = w & 1;  // wave quadrant (64x64)

  f32x4 acc[4][4] = {};
  f32x4 accc[4][4] = {};

  for (int k0 = 0; k0 < K; k0 += 64) {
    const _Float16* sp = stage_src + k0 + laneoff;
#pragma unroll
    for (int q = 0; q < 16; ++q)
      gload16(sp + (size_t)q * 8 * strideA, stage_dst + q * 512);
    __syncthreads();

#pragma unroll
    for (int kk = 0; kk < 2; ++kk) {
      half8 ah[4], al[4], bh[4], bl[4];
#pragma unroll
      for (int mi = 0; mi < 4; ++mi) {
        int row = wm * 64 + mi * 16 + l15;
        int off = row * 64 + (((kk * 4 + g4) ^ (l15 & 7)) * 8);
        ah[mi] = *(const half8*)&lds[off];
        al[mi] = *(const half8*)&lds[8192 + off];
      }
#pragma unroll
      for (int ni = 0; ni < 4; ++ni) {
        int row = wn * 64 + ni * 16 + l15;
        int off = row * 64 + (((kk * 4 + g4) ^ (l15 & 7)) * 8);
        bh[ni] = *(const half8*)&lds[16384 + off];
        bl[ni] = *(const half8*)&lds[24576 + off];
      }
#pragma unroll
      for (int mi = 0; mi < 4; ++mi)
#pragma unroll
        for (int ni = 0; ni < 4; ++ni) {
          acc[mi][ni]  = __builtin_amdgcn_mfma_f32_16x16x32_f16(ah[mi], bh[ni], acc[mi][ni], 0, 0, 0);
          accc[mi][ni] = __builtin_amdgcn_mfma_f32_16x16x32_f16(ah[mi], bl[ni], accc[mi][ni], 0, 0, 0);
          accc[mi][ni] = __builtin_amdgcn_mfma_f32_16x16x32_f16(al[mi], bh[ni], accc[mi][ni], 0, 0, 0);
        }
    }
    __syncthreads();
  }

#pragma unroll
  for (int mi = 0; mi < 4; ++mi)
#pragma unroll
    for (int ni = 0; ni < 4; ++ni)
#pragma unroll
      for (int r = 0; r < 4; ++r) {
        int m = m0 + wm * 64 + mi * 16 + g4 * 4 + r;
        int n = n0 + wn * 64 + ni * 16 + l15;
        float c = acc[mi][ni][r] + accc[mi][ni][r] * (1.0f / 2048.0f);
        size_t idx = (size_t)m * ldc + n;
        if (EPI == 0) {
          float bv = (n < nsplit) ? bias[n] : bias2[n - nsplit];
          c = fmaxf(c + bv, 0.0f);
          _Float16 hi, lo; split2(c, hi, lo);
          Ch[idx] = hi; Cl[idx] = lo;
        } else if (EPI == 1) {
          float bv = (n < nsplit) ? bias[n] : bias2[n - nsplit];
          Cf[idx] = c + bv;
        } else {
          Cf[idx] = 2.0f * c - rown[m] - coln[n];
        }
      }
}

// ---------------------------------------------------------------------------
// Z = mu + softplus(ps)*eps ; MPS holds [mu | ps] per row (ld 1024).
// writes mu,Z (fp32 out), Z split pair, ||Z||^2
// ---------------------------------------------------------------------------
__global__ __launch_bounds__(256) void kz_kernel(const float* __restrict__ MPS,
                                                 const float* __restrict__ eps,
                                                 float* __restrict__ out,
                                                 _Float16* __restrict__ Zh,
                                                 _Float16* __restrict__ Zl,
                                                 float* __restrict__ z2) {
  __shared__ float sh[4];
  int row = blockIdx.x, t = threadIdx.x;
  float s = 0.f;
  for (int j = t; j < D_; j += 256) {
    size_t idx = (size_t)row * D_ + j;
    float m = MPS[(size_t)row * 1024 + j];
    float p = MPS[(size_t)row * 1024 + 512 + j];
    float e = eps[idx];
    float sp = fmaxf(p, 0.f) + log1pf(expf(-fabsf(p)));  // stable softplus
    float z = m + sp * e;
    out[O_MU + idx] = m;
    out[O_Z + idx] = z;
    _Float16 hi, lo; split2(z, hi, lo);
    Zh[idx] = hi; Zl[idx] = lo;
    s += z * z;
  }
#pragma unroll
  for (int o = 32; o; o >>= 1) s += __shfl_xor(s, o);
  if ((t & 63) == 0) sh[t >> 6] = s;
  __syncthreads();
  if (t == 0) z2[row] = (sh[0] + sh[1]) + (sh[2] + sh[3]);
}

// ---------------------------------------------------------------------------
// fused fine+coarse routing (one block per batch row):
//  - fine: double softmax + gumbel + argmax over S=4096; logits are READ from
//    out[O_SOFT] (written there by the dist GEMM) into registers, then the
//    same slots are overwritten with the final soft probs. Block-local, safe.
//  - coarse: ky logic as a tail (Y=256=blockDim), using the in-block fine idx.
// ---------------------------------------------------------------------------
__global__ __launch_bounds__(256) void ks_kernel(const float* __restrict__ us,
                                                 const float* __restrict__ lzy,
                                                 const float* __restrict__ lsy,
                                                 const float* __restrict__ uy,
                                                 float* __restrict__ out) {
  __shared__ float shf[4];
  __shared__ int shi[4];
  int row = blockIdx.x, t = threadIdx.x;
  const float4* l4 = (const float4*)(out + O_SOFT + (size_t)row * S_) + t * 4;
  const float4* u4 = (const float4*)(us + (size_t)row * S_) + t * 4;

  float v[16];
#pragma unroll
  for (int q = 0; q < 4; ++q) {
    float4 x = l4[q];
    v[q * 4 + 0] = x.x; v[q * 4 + 1] = x.y; v[q * 4 + 2] = x.z; v[q * 4 + 3] = x.w;
  }
  float m1 = -3.4e38f;
#pragma unroll
  for (int k = 0; k < 16; ++k) m1 = fmaxf(m1, v[k]);
  m1 = blockMax(m1, shf);
  float s1 = 0.f;
#pragma unroll
  for (int k = 0; k < 16; ++k) { v[k] = __expf(v[k] - m1); s1 += v[k]; }
  s1 = blockSum(s1, shf);
  float is1 = 1.0f / s1;
  float m2 = -3.4e38f;
#pragma unroll
  for (int q = 0; q < 4; ++q) {
    float4 uu = u4[q];
    float ua[4] = {uu.x, uu.y, uu.z, uu.w};
#pragma unroll
    for (int e = 0; e < 4; ++e) {
      int k = q * 4 + e;
      float p = v[k] * is1 + 1e-9f;                    // softmax + 1e-9
      float g = -logf(-logf(ua[e] + 1e-20f) + 1e-20f); // gumbel (precise logs)
      v[k] = (logf(p) + g) * 2.0f;                     // (log p + g)/0.5
      m2 = fmaxf(m2, v[k]);
    }
  }
  m2 = blockMax(m2, shf);
  float s2 = 0.f;
#pragma unroll
  for (int k = 0; k < 16; ++k) { v[k] = __expf(v[k] - m2); s2 += v[k]; }
  s2 = blockSum(s2, shf);
  float is2 = 1.0f / s2;
  float bv = -3.4e38f; int bi = 0x7fffffff;
  float* so = out + O_SOFT + (size_t)row * S_ + (size_t)t * 16;
#pragma unroll
  for (int q = 0; q < 4; ++q) {
    float pe[4];
#pragma unroll
    for (int e = 0; e < 4; ++e) {
      int k = q * 4 + e;
      pe[e] = v[k] * is2;
      if (pe[e] > bv) { bv = pe[e]; bi = t * 16 + k; } // ascending j: > keeps first
    }
    float4 pv; pv.x = pe[0]; pv.y = pe[1]; pv.z = pe[2]; pv.w = pe[3];
    ((float4*)so)[q] = pv;
  }
  blockArgmax(bv, bi, shf, shi);
  float* ho = out + O_HARD + (size_t)row * S_ + (size_t)t * 16;
#pragma unroll
  for (int q = 0; q < 4; ++q) {
    float4 hv;
    hv.x = (t * 16 + q * 4 + 0 == bi) ? 1.f : 0.f;
    hv.y = (t * 16 + q * 4 + 1 == bi) ? 1.f : 0.f;
    hv.z = (t * 16 + q * 4 + 2 == bi) ? 1.f : 0.f;
    hv.w = (t * 16 + q * 4 + 3 == bi) ? 1.f : 0.f;
    ((float4*)ho)[q] = hv;
  }

  // ---- coarse tail (ky): all threads hold bi == fine index ----
  float lc = 0.5f * (lzy[(size_t)row * Y_ + t] + lsy[(size_t)bi * Y_ + t]);
  float cm1 = blockMax(lc, shf);
  float ce = __expf(lc - cm1);
  float cs1 = blockSum(ce, shf);
  float cp = ce / cs1 + 1e-9f;
  float cg = -logf(-logf(uy[(size_t)row * Y_ + t] + 1e-20f) + 1e-20f);
  float ca = (logf(cp) + cg) * 2.0f;
  float cm2 = blockMax(ca, shf);
  float cy = __expf(ca - cm2);
  float cs2 = blockSum(cy, shf);
  float csp = cy / cs2;
  out[O_SOFTY + (size_t)row * Y_ + t] = csp;
  float cbv = csp; int cbi = t;
  blockArgmax(cbv, cbi, shf, shi);
  if (t == 0) out[O_BY + row] = (float)cbi;
}

// ---------------------------------------------------------------------------
// launch
// ---------------------------------------------------------------------------
extern "C" void kernel_launch(void* const* d_in, const int* in_sizes, int n_in,
                              void* d_out, int out_size, void* d_ws, size_t ws_size,
                              hipStream_t stream) {
  const float* X    = (const float*)d_in[0];
  const float* W1   = (const float*)d_in[1];
  const float* b1   = (const float*)d_in[2];
  const float* W2   = (const float*)d_in[3];
  const float* b2   = (const float*)d_in[4];
  const float* Ws1  = (const float*)d_in[5];
  const float* bs1  = (const float*)d_in[6];
  const float* Ws2  = (const float*)d_in[7];
  const float* bs2  = (const float*)d_in[8];
  const float* mu_y = (const float*)d_in[9];
  const float* mu_s = (const float*)d_in[10];
  const float* eps  = (const float*)d_in[11];
  const float* u_s  = (const float*)d_in[12];
  const float* u_y  = (const float*)d_in[13];
  float* out = (float*)d_out;   // OUTPUT dtype is FLOAT32

  // ---- workspace layout (peak 151.6 MB; ws >= 164 MB verified in R4) ----
  // Region A [0, 125.83 MB): encoder temporaries, dead after kz.
  // After kz, A-span reuse: LZY@0 (8192x256 f32), LSY@8,388,608 (4096x256 f32)
  //   -- contiguous so the fused coarse GEMM writes Cf[m*256+n], m in [0,12288).
  // Raw fine LOGITS live in d_out's soft_prob slot (overwritten by ks).
  char* ws = (char*)d_ws;
  _Float16* XH    = (_Float16*)(ws + 0);            //  8,388,608
  _Float16* XL    = (_Float16*)(ws + 8388608);
  _Float16* W1CH  = (_Float16*)(ws + 16777216);     //  2,097,152  [2048][512] cat(W1T,Ws1T)
  _Float16* W1CL  = (_Float16*)(ws + 18874368);
  _Float16* W2CH  = (_Float16*)(ws + 20971520);     //  2,097,152  [1024][1024] cat(W2T,Ws2T)
  _Float16* W2CL  = (_Float16*)(ws + 23068672);
  _Float16* H1H   = (_Float16*)(ws + 25165824);     // 33,554,432  [8192][2048]
  _Float16* H1L   = (_Float16*)(ws + 58720256);
  float*    MPS   = (float*)  (ws + 92274688);      // 33,554,432  [8192][1024] = [mu|ps]
  float*    LZY   = (float*)  (ws + 0);             //  8,388,608 (post-kz reuse)
  float*    LSY   = (float*)  (ws + 8388608);       //  4,194,304 (contiguous after LZY)
  // Region B @125.83 MB (live across dist GEMMs + routing).
  // [ZH|MSH] and [ZL|MSL] contiguous -> coarse-GEMM A is one 12288x512 matrix.
  // [Z2|CS2] contiguous -> coarse-GEMM rown is one 12288-vector.
  const size_t RB = 125829120;
  _Float16* ZH   = (_Float16*)(ws + RB + 0);         //  8,388,608
  _Float16* MSH  = (_Float16*)(ws + RB + 8388608);   //  4,194,304
  _Float16* ZL   = (_Float16*)(ws + RB + 12582912);  //  8,388,608
  _Float16* MSL  = (_Float16*)(ws + RB + 20971520);  //  4,194,304
  _Float16* MYH  = (_Float16*)(ws + RB + 25165824);  //    262,144
  _Float16* MYL  = (_Float16*)(ws + RB + 25427968);  //    262,144
  float*    Z2   = (float*)  (ws + RB + 25690112);   //     32,768
  float*    CS2  = (float*)  (ws + RB + 25722880);   //     16,384 (contiguous after Z2)
  float*    CY2  = (float*)  (ws + RB + 25739264);   //      4,096 -> end 151,572,480
  (void)ws_size; (void)in_sizes; (void)n_in; (void)out_size;

  float* LOGITS = out + O_SOFT;  // raw fine logits staged in the soft_prob slot

  // 1) fused prep (splits + transpose-splits + codebook norms) — one dispatch
  prep_kernel<<<3920, 256, 0, stream>>>(X, W1, Ws1, W2, Ws2, mu_s, mu_y,
                                        XH, XL, MSH, MSL, MYH, MYL,
                                        W1CH, W1CL, W2CH, W2CL, CS2, CY2);

  // 2) encoder layer 1 (fused heads: N = 2048 = cat(H1, S1)), relu+split epi
  gemm_split<0><<<dim3(2 * H_ / 128, B_ / 128), 256, 0, stream>>>(
      XH, XL, W1CH, W1CL, 2 * H_, D_, D_, 2 * H_, H_, 0,
      b1, bs1, nullptr, H1H, H1L, nullptr, nullptr);

  // 3) encoder layer 2 (fused heads: N = 1024 = cat(mu, ps); A-col switch at 512)
  gemm_split<1><<<dim3(2 * D_ / 128, B_ / 128), 256, 0, stream>>>(
      H1H, H1L, W2CH, W2CL, 2 * D_, H_, 2 * H_, 2 * D_, D_, H_,
      b2, bs2, MPS, nullptr, nullptr, nullptr, nullptr);

  // 4) reparameterize (region A dead after this)
  kz_kernel<<<B_, 256, 0, stream>>>(MPS, eps, out, ZH, ZL, Z2);

  // 5) fine logits, full size, written into out's soft_prob slot
  gemm_split<2><<<dim3(S_ / 128, B_ / 128), 256, 0, stream>>>(
      ZH, ZL, MSH, MSL, S_, D_, D_, S_, S_, 0,
      nullptr, nullptr, LOGITS, nullptr, nullptr, Z2, CS2);

  // 6) coarse logits, fused: A = [Z; mu_s] (12288 x 512), C = [LZY; LSY]
  gemm_split<2><<<dim3(Y_ / 128, (B_ + S_) / 128), 256, 0, stream>>>(
      ZH, ZL, MYH, MYL, Y_, D_, D_, Y_, Y_, 0,
      nullptr, nullptr, LZY, nullptr, nullptr, Z2, CY2);

  // 7) fused fine+coarse routing
  ks_kernel<<<B_, 256, 0, stream>>>(u_s, LZY, LSY, u_y, out);
}